// Round 2
// baseline (978.834 us; speedup 1.0000x reference)
//
#include <hip/hip_runtime.h>
#include <math.h>

// GraphSAGE 2-layer + MLP head + softmax(2), CSR pull-mode aggregation.
// x[N,48] f32, edge_index[2,E] int32, weights f32, out[N,2] f32.

#define NF1 48
#define HH 64

__global__ __launch_bounds__(256) void k_hist(const int* __restrict__ ei,
                                              int* __restrict__ hist, int E) {
  int e = blockIdx.x * 256 + threadIdx.x;
  if (e < E) atomicAdd(&hist[ei[E + e]], 1);
}

// block-level exclusive scan (256 elems/block), in-place, block totals to bsum
__global__ __launch_bounds__(256) void k_scan1(int* __restrict__ rp,
                                               int* __restrict__ bsum, int Nn) {
  __shared__ int a[256], b[256];
  int tid = threadIdx.x;
  int i = blockIdx.x * 256 + tid;
  int v = (i < Nn) ? rp[i] : 0;
  a[tid] = v;
  __syncthreads();
  int* s = a;
  int* d = b;
  for (int off = 1; off < 256; off <<= 1) {
    int t = s[tid] + ((tid >= off) ? s[tid - off] : 0);
    d[tid] = t;
    __syncthreads();
    int* tmp = s; s = d; d = tmp;
  }
  int incl = s[tid];
  if (i < Nn) rp[i] = incl - v;
  if (tid == 255) bsum[blockIdx.x] = incl;
}

__global__ void k_scan2(int* __restrict__ bsum, int nb) {
  if (threadIdx.x == 0 && blockIdx.x == 0) {
    int run = 0;
    for (int i = 0; i < nb; i++) { int t = bsum[i]; bsum[i] = run; run += t; }
  }
}

__global__ __launch_bounds__(256) void k_scan3(int* __restrict__ rp,
                                               int* __restrict__ cursor,
                                               const int* __restrict__ bsum,
                                               int Nn, int E) {
  int i = blockIdx.x * 256 + threadIdx.x;
  if (i < Nn) {
    int v = rp[i] + bsum[blockIdx.x];
    rp[i] = v;
    cursor[i] = v;
  }
  if (i == 0) rp[Nn] = E;
}

__global__ __launch_bounds__(256) void k_scatter(const int* __restrict__ ei,
                                                 int* __restrict__ cursor,
                                                 int* __restrict__ csr, int E) {
  int e = blockIdx.x * 256 + threadIdx.x;
  if (e >= E) return;
  int s = ei[e], d2 = ei[E + e];
  int idx = atomicAdd(&cursor[d2], 1);
  csr[idx] = s;
}

// h1 = sigmoid(mean(x[nbrs]) @ W1l + b1l + x @ W1r), one wave per node
__global__ __launch_bounds__(256) void node1_fused(
    const float* __restrict__ x, const int* __restrict__ rp,
    const int* __restrict__ csr,
    const float* __restrict__ W1l, const float* __restrict__ b1l,
    const float* __restrict__ W1r,
    float* __restrict__ h1, int n_nodes) {
  __shared__ float sWl[NF1 * HH];
  __shared__ float sWr[NF1 * HH];
  __shared__ float sb[HH];
  __shared__ float sm[4][NF1];
  __shared__ float sx[4][NF1];
  for (int i = threadIdx.x; i < NF1 * HH; i += 256) {
    sWl[i] = W1l[i];
    sWr[i] = W1r[i];
  }
  if (threadIdx.x < HH) sb[threadIdx.x] = b1l[threadIdx.x];
  __syncthreads();

  int wave = threadIdx.x >> 6, lane = threadIdx.x & 63;
  int node = blockIdx.x * 4 + wave;
  bool valid = node < n_nodes;
  int nn = valid ? node : 0;
  int rs = rp[nn], re = rp[nn + 1];
  if (lane < NF1) {
    float s = 0.0f;
    for (int i = rs; i < re; i++) {
      int src = csr[i];
      s += x[(long long)src * NF1 + lane];
    }
    float inv = 1.0f / fmaxf((float)(re - rs), 1.0f);
    sm[wave][lane] = s * inv;
    sx[wave][lane] = x[(long long)nn * NF1 + lane];
  }
  __syncthreads();

  float acc = sb[lane];
#pragma unroll
  for (int k = 0; k < NF1; k++) {
    acc += sm[wave][k] * sWl[k * HH + lane] + sx[wave][k] * sWr[k * HH + lane];
  }
  if (valid) h1[(long long)node * HH + lane] = 1.0f / (1.0f + __expf(-acc));
}

// h2 = sigmoid(mean(h1[nbrs]) @ W2l + b2l + h1 @ W2r)
// h3 = sigmoid(h2 @ Wlin1 + blin1); out = softmax(h3 @ Wlin2 + blin2)
__global__ __launch_bounds__(256) void node2_fused(
    const float* __restrict__ h1, const int* __restrict__ rp,
    const int* __restrict__ csr,
    const float* __restrict__ W2l, const float* __restrict__ b2l,
    const float* __restrict__ W2r,
    const float* __restrict__ Wlin1, const float* __restrict__ blin1,
    const float* __restrict__ Wlin2, const float* __restrict__ blin2,
    float* __restrict__ out, int n_nodes) {
  __shared__ float sW2l[HH * HH];
  __shared__ float sW2r[HH * HH];
  __shared__ float sWl1[HH * HH];
  __shared__ float sWl2[HH * 2];
  __shared__ float sb2[HH], sbl1[HH], sbl2[2];
  __shared__ float sm[4][HH];
  __shared__ float sh[4][HH];
  __shared__ float sh2[4][HH];
  for (int i = threadIdx.x; i < HH * HH; i += 256) {
    sW2l[i] = W2l[i];
    sW2r[i] = W2r[i];
    sWl1[i] = Wlin1[i];
  }
  if (threadIdx.x < HH * 2) sWl2[threadIdx.x] = Wlin2[threadIdx.x];
  if (threadIdx.x < HH) {
    sb2[threadIdx.x] = b2l[threadIdx.x];
    sbl1[threadIdx.x] = blin1[threadIdx.x];
  }
  if (threadIdx.x < 2) sbl2[threadIdx.x] = blin2[threadIdx.x];
  __syncthreads();

  int wave = threadIdx.x >> 6, lane = threadIdx.x & 63;
  int node = blockIdx.x * 4 + wave;
  bool valid = node < n_nodes;
  int nn = valid ? node : 0;
  int rs = rp[nn], re = rp[nn + 1];
  {
    float s = 0.0f;
    for (int i = rs; i < re; i++) {
      int src = csr[i];
      s += h1[(long long)src * HH + lane];
    }
    float inv = 1.0f / fmaxf((float)(re - rs), 1.0f);
    sm[wave][lane] = s * inv;
    sh[wave][lane] = h1[(long long)nn * HH + lane];
  }
  __syncthreads();

  // h2
  {
    float acc = sb2[lane];
#pragma unroll
    for (int k = 0; k < HH; k++) {
      acc += sm[wave][k] * sW2l[k * HH + lane] + sh[wave][k] * sW2r[k * HH + lane];
    }
    sh2[wave][lane] = 1.0f / (1.0f + __expf(-acc));
  }
  __syncthreads();

  // h3 (register) from sh2
  float acc = sbl1[lane];
#pragma unroll
  for (int k = 0; k < HH; k++) {
    acc += sh2[wave][k] * sWl1[k * HH + lane];
  }
  float h3 = 1.0f / (1.0f + __expf(-acc));

  // logits: per-lane partials, wave reduce
  float l0 = h3 * sWl2[lane * 2 + 0];
  float l1 = h3 * sWl2[lane * 2 + 1];
  for (int off = 32; off > 0; off >>= 1) {
    l0 += __shfl_xor(l0, off);
    l1 += __shfl_xor(l1, off);
  }
  if (valid && lane == 0) {
    l0 += sbl2[0];
    l1 += sbl2[1];
    float m = fmaxf(l0, l1);
    float p0 = __expf(l0 - m), p1 = __expf(l1 - m);
    float s = 1.0f / (p0 + p1);
    out[(long long)node * 2 + 0] = p0 * s;
    out[(long long)node * 2 + 1] = p1 * s;
  }
}

extern "C" void kernel_launch(void* const* d_in, const int* in_sizes, int n_in,
                              void* d_out, int out_size, void* d_ws, size_t ws_size,
                              hipStream_t stream) {
  const float* x     = (const float*)d_in[0];
  const int*   ei    = (const int*)d_in[1];
  const float* W1l   = (const float*)d_in[2];
  const float* b1l   = (const float*)d_in[3];
  const float* W1r   = (const float*)d_in[4];
  const float* W2l   = (const float*)d_in[5];
  const float* b2l   = (const float*)d_in[6];
  const float* W2r   = (const float*)d_in[7];
  const float* Wlin1 = (const float*)d_in[8];
  const float* blin1 = (const float*)d_in[9];
  const float* Wlin2 = (const float*)d_in[10];
  const float* blin2 = (const float*)d_in[11];
  float* out = (float*)d_out;

  int n = in_sizes[0] / NF1;
  int E = in_sizes[1] / 2;
  int nb = (n + 255) / 256;

  int* rp     = (int*)d_ws;                 // [n+1] hist -> row_ptr
  int* cursor = rp + (n + 1);               // [n]
  int* bsum   = cursor + n;                 // [nb]
  int* csr    = bsum + nb;                  // [E]
  float* h1   = (float*)(csr + E);          // [n,64]

  hipMemsetAsync(rp, 0, (size_t)(n + 1) * sizeof(int), stream);

  int eb = (E + 255) / 256;
  k_hist<<<eb, 256, 0, stream>>>(ei, rp, E);
  k_scan1<<<nb, 256, 0, stream>>>(rp, bsum, n);
  k_scan2<<<1, 64, 0, stream>>>(bsum, nb);
  k_scan3<<<nb, 256, 0, stream>>>(rp, cursor, bsum, n, E);
  k_scatter<<<eb, 256, 0, stream>>>(ei, cursor, csr, E);

  node1_fused<<<(n + 3) / 4, 256, 0, stream>>>(x, rp, csr, W1l, b1l, W1r, h1, n);
  node2_fused<<<(n + 3) / 4, 256, 0, stream>>>(h1, rp, csr, W2l, b2l, W2r,
                                               Wlin1, blin1, Wlin2, blin2, out, n);
}

// Round 3
// 582.120 us; speedup vs baseline: 1.6815x; 1.6815x over previous
//
#include <hip/hip_runtime.h>
#include <math.h>

// GraphSAGE 2-layer + MLP head + softmax(2), CSR pull-mode aggregation.
// x[N,48] f32, edge_index[2,E] int32, weights f32, out[N,2] f32.

#define NF1 48
#define HH 64

__global__ __launch_bounds__(256) void k_hist(const int* __restrict__ ei,
                                              int* __restrict__ hist, int E) {
  int e = blockIdx.x * 256 + threadIdx.x;
  if (e < E) atomicAdd(&hist[ei[E + e]], 1);
}

__global__ __launch_bounds__(256) void k_scan1(int* __restrict__ rp,
                                               int* __restrict__ bsum, int Nn) {
  __shared__ int a[256], b[256];
  int tid = threadIdx.x;
  int i = blockIdx.x * 256 + tid;
  int v = (i < Nn) ? rp[i] : 0;
  a[tid] = v;
  __syncthreads();
  int* s = a;
  int* d = b;
  for (int off = 1; off < 256; off <<= 1) {
    int t = s[tid] + ((tid >= off) ? s[tid - off] : 0);
    d[tid] = t;
    __syncthreads();
    int* tmp = s; s = d; d = tmp;
  }
  int incl = s[tid];
  if (i < Nn) rp[i] = incl - v;
  if (tid == 255) bsum[blockIdx.x] = incl;
}

__global__ void k_scan2(int* __restrict__ bsum, int nb) {
  if (threadIdx.x == 0 && blockIdx.x == 0) {
    int run = 0;
    for (int i = 0; i < nb; i++) { int t = bsum[i]; bsum[i] = run; run += t; }
  }
}

__global__ __launch_bounds__(256) void k_scan3(int* __restrict__ rp,
                                               int* __restrict__ cursor,
                                               const int* __restrict__ bsum,
                                               int Nn, int E) {
  int i = blockIdx.x * 256 + threadIdx.x;
  if (i < Nn) {
    int v = rp[i] + bsum[blockIdx.x];
    rp[i] = v;
    cursor[i] = v;
  }
  if (i == 0) rp[Nn] = E;
}

__global__ __launch_bounds__(256) void k_scatter(const int* __restrict__ ei,
                                                 int* __restrict__ cursor,
                                                 int* __restrict__ csr, int E) {
  int e = blockIdx.x * 256 + threadIdx.x;
  if (e >= E) return;
  int s = ei[e], d2 = ei[E + e];
  int idx = atomicAdd(&cursor[d2], 1);
  csr[idx] = s;
}

__device__ __forceinline__ float sigmoidf_(float v) {
  return 1.0f / (1.0f + __expf(-v));
}

// h1 = sigmoid(mean(x[nbrs]) @ W1l + b1l + x @ W1r). 8 waves/block, 1 node/wave.
__global__ __launch_bounds__(512) void node1_fused(
    const float* __restrict__ x, const int* __restrict__ rp,
    const int* __restrict__ csr,
    const float* __restrict__ W1l, const float* __restrict__ b1l,
    const float* __restrict__ W1r,
    float* __restrict__ h1, int n_nodes) {
  __shared__ float sWl[NF1 * HH];
  __shared__ float sWr[NF1 * HH];
  __shared__ float sb[HH];
  __shared__ float sm[8][NF1];
  __shared__ float sx[8][NF1];
  for (int i = threadIdx.x; i < NF1 * HH; i += 512) {
    sWl[i] = W1l[i];
    sWr[i] = W1r[i];
  }
  if (threadIdx.x < HH) sb[threadIdx.x] = b1l[threadIdx.x];
  __syncthreads();

  int wv = threadIdx.x >> 6, lane = threadIdx.x & 63;
  int node = blockIdx.x * 8 + wv;
  bool valid = node < n_nodes;
  int nn = valid ? node : 0;
  int rs = rp[nn], re = rp[nn + 1];
  int g = lane >> 4, fl = lane & 15;

  float ax = 0.0f, ay = 0.0f, az = 0.0f, aw = 0.0f;
  if (fl < 12) {
    int i = rs + g;
    for (; i + 4 < re; i += 8) {
      int s0 = csr[i];
      int s1 = csr[i + 4];
      float4 v0 = *((const float4*)(x + (size_t)s0 * NF1) + fl);
      float4 v1 = *((const float4*)(x + (size_t)s1 * NF1) + fl);
      ax += v0.x + v1.x; ay += v0.y + v1.y;
      az += v0.z + v1.z; aw += v0.w + v1.w;
    }
    for (; i < re; i += 4) {
      int s0 = csr[i];
      float4 v0 = *((const float4*)(x + (size_t)s0 * NF1) + fl);
      ax += v0.x; ay += v0.y; az += v0.z; aw += v0.w;
    }
  }
  // reduce across the 4 groups
  ax += __shfl_xor(ax, 16); ay += __shfl_xor(ay, 16);
  az += __shfl_xor(az, 16); aw += __shfl_xor(aw, 16);
  ax += __shfl_xor(ax, 32); ay += __shfl_xor(ay, 32);
  az += __shfl_xor(az, 32); aw += __shfl_xor(aw, 32);

  float inv = 1.0f / fmaxf((float)(re - rs), 1.0f);
  if (lane < 12) {
    float4 m4 = {ax * inv, ay * inv, az * inv, aw * inv};
    ((float4*)sm[wv])[lane] = m4;
  }
  if (lane < NF1) sx[wv][lane] = x[(size_t)nn * NF1 + lane];
  __syncthreads();

  float acc = sb[lane];
#pragma unroll
  for (int k = 0; k < NF1; k++) {
    acc += sm[wv][k] * sWl[k * HH + lane] + sx[wv][k] * sWr[k * HH + lane];
  }
  if (valid) h1[(size_t)node * HH + lane] = sigmoidf_(acc);
}

// h2 = sigmoid(mean(h1[nbrs]) @ W2l + b2l + h1 @ W2r)
// h3 = sigmoid(h2 @ Wlin1 + blin1)   (via __shfl broadcast of lane-local h2)
// out = softmax(h3 @ Wlin2 + blin2)
__global__ __launch_bounds__(512) void node2_fused(
    const float* __restrict__ h1, const int* __restrict__ rp,
    const int* __restrict__ csr,
    const float* __restrict__ W2l, const float* __restrict__ b2l,
    const float* __restrict__ W2r,
    const float* __restrict__ Wlin1, const float* __restrict__ blin1,
    const float* __restrict__ Wlin2, const float* __restrict__ blin2,
    float* __restrict__ out, int n_nodes) {
  __shared__ float sW2l[HH * HH];
  __shared__ float sW2r[HH * HH];
  __shared__ float sWl1[HH * HH];
  __shared__ float sWl2[HH * 2];
  __shared__ float sb2[HH], sbl1[HH], sbl2[2];
  __shared__ float sm[8][HH];
  __shared__ float sh[8][HH];
  for (int i = threadIdx.x; i < HH * HH; i += 512) {
    sW2l[i] = W2l[i];
    sW2r[i] = W2r[i];
    sWl1[i] = Wlin1[i];
  }
  if (threadIdx.x < HH * 2) sWl2[threadIdx.x] = Wlin2[threadIdx.x];
  if (threadIdx.x < HH) {
    sb2[threadIdx.x] = b2l[threadIdx.x];
    sbl1[threadIdx.x] = blin1[threadIdx.x];
  }
  if (threadIdx.x < 2) sbl2[threadIdx.x] = blin2[threadIdx.x];
  __syncthreads();

  int wv = threadIdx.x >> 6, lane = threadIdx.x & 63;
  int node = blockIdx.x * 8 + wv;
  bool valid = node < n_nodes;
  int nn = valid ? node : 0;
  int rs = rp[nn], re = rp[nn + 1];
  int g = lane >> 4, fl = lane & 15;

  float ax = 0.0f, ay = 0.0f, az = 0.0f, aw = 0.0f;
  {
    int i = rs + g;
    for (; i + 4 < re; i += 8) {
      int s0 = csr[i];
      int s1 = csr[i + 4];
      float4 v0 = *((const float4*)(h1 + (size_t)s0 * HH) + fl);
      float4 v1 = *((const float4*)(h1 + (size_t)s1 * HH) + fl);
      ax += v0.x + v1.x; ay += v0.y + v1.y;
      az += v0.z + v1.z; aw += v0.w + v1.w;
    }
    for (; i < re; i += 4) {
      int s0 = csr[i];
      float4 v0 = *((const float4*)(h1 + (size_t)s0 * HH) + fl);
      ax += v0.x; ay += v0.y; az += v0.z; aw += v0.w;
    }
  }
  ax += __shfl_xor(ax, 16); ay += __shfl_xor(ay, 16);
  az += __shfl_xor(az, 16); aw += __shfl_xor(aw, 16);
  ax += __shfl_xor(ax, 32); ay += __shfl_xor(ay, 32);
  az += __shfl_xor(az, 32); aw += __shfl_xor(aw, 32);

  float inv = 1.0f / fmaxf((float)(re - rs), 1.0f);
  if (lane < 16) {
    float4 m4 = {ax * inv, ay * inv, az * inv, aw * inv};
    ((float4*)sm[wv])[lane] = m4;
  }
  sh[wv][lane] = h1[(size_t)nn * HH + lane];
  __syncthreads();

  // h2 for output feature j = lane
  float acc = sb2[lane];
#pragma unroll
  for (int k = 0; k < HH; k++) {
    acc += sm[wv][k] * sW2l[k * HH + lane] + sh[wv][k] * sW2r[k * HH + lane];
  }
  float v2 = sigmoidf_(acc);

  // h3 via __shfl broadcast of v2 across the wave
  float acc3 = sbl1[lane];
#pragma unroll
  for (int k = 0; k < HH; k++) {
    acc3 += __shfl(v2, k) * sWl1[k * HH + lane];
  }
  float h3 = sigmoidf_(acc3);

  // logits: per-lane partials, wave reduce
  float l0 = h3 * sWl2[lane * 2 + 0];
  float l1 = h3 * sWl2[lane * 2 + 1];
  for (int off = 32; off > 0; off >>= 1) {
    l0 += __shfl_xor(l0, off);
    l1 += __shfl_xor(l1, off);
  }
  if (valid && lane == 0) {
    l0 += sbl2[0];
    l1 += sbl2[1];
    float m = fmaxf(l0, l1);
    float p0 = __expf(l0 - m), p1 = __expf(l1 - m);
    float s = 1.0f / (p0 + p1);
    out[(size_t)node * 2 + 0] = p0 * s;
    out[(size_t)node * 2 + 1] = p1 * s;
  }
}

extern "C" void kernel_launch(void* const* d_in, const int* in_sizes, int n_in,
                              void* d_out, int out_size, void* d_ws, size_t ws_size,
                              hipStream_t stream) {
  const float* x     = (const float*)d_in[0];
  const int*   ei    = (const int*)d_in[1];
  const float* W1l   = (const float*)d_in[2];
  const float* b1l   = (const float*)d_in[3];
  const float* W1r   = (const float*)d_in[4];
  const float* W2l   = (const float*)d_in[5];
  const float* b2l   = (const float*)d_in[6];
  const float* W2r   = (const float*)d_in[7];
  const float* Wlin1 = (const float*)d_in[8];
  const float* blin1 = (const float*)d_in[9];
  const float* Wlin2 = (const float*)d_in[10];
  const float* blin2 = (const float*)d_in[11];
  float* out = (float*)d_out;

  int n = in_sizes[0] / NF1;
  int E = in_sizes[1] / 2;
  int nb = (n + 255) / 256;

  int* rp     = (int*)d_ws;                 // [n+1] hist -> row_ptr
  int* cursor = rp + (n + 1);               // [n]
  int* bsum   = cursor + n;                 // [nb]
  int* csr    = bsum + nb;                  // [E]
  // align h1 to 256B
  size_t h1_off = (size_t)(n + 1 + n + nb + E) * sizeof(int);
  h1_off = (h1_off + 255) & ~(size_t)255;
  float* h1 = (float*)((char*)d_ws + h1_off);  // [n,64]

  hipMemsetAsync(rp, 0, (size_t)(n + 1) * sizeof(int), stream);

  int eb = (E + 255) / 256;
  k_hist<<<eb, 256, 0, stream>>>(ei, rp, E);
  k_scan1<<<nb, 256, 0, stream>>>(rp, bsum, n);
  k_scan2<<<1, 64, 0, stream>>>(bsum, nb);
  k_scan3<<<nb, 256, 0, stream>>>(rp, cursor, bsum, n, E);
  k_scatter<<<eb, 256, 0, stream>>>(ei, cursor, csr, E);

  int nodeb = (n + 7) / 8;
  node1_fused<<<nodeb, 512, 0, stream>>>(x, rp, csr, W1l, b1l, W1r, h1, n);
  node2_fused<<<nodeb, 512, 0, stream>>>(h1, rp, csr, W2l, b2l, W2r,
                                         Wlin1, blin1, Wlin2, blin2, out, n);
}

// Round 4
// 462.882 us; speedup vs baseline: 2.1147x; 1.2576x over previous
//
#include <hip/hip_runtime.h>
#include <math.h>

// GraphSAGE 2-layer + MLP head + softmax(2), CSR pull-mode aggregation.
// x[N,48] f32, edge_index[2,E] int32, weights f32, out[N,2] f32.
// h1 stored bf16 (raw ushort) to halve layer-2 gather traffic.

#define NF1 48
#define HH 64

__global__ __launch_bounds__(256) void k_hist(const int* __restrict__ ei,
                                              int* __restrict__ hist, int E) {
  int e = blockIdx.x * 256 + threadIdx.x;
  if (e < E) atomicAdd(&hist[ei[E + e]], 1);
}

__global__ __launch_bounds__(256) void k_scan1(int* __restrict__ rp,
                                               int* __restrict__ bsum, int Nn) {
  __shared__ int a[256], b[256];
  int tid = threadIdx.x;
  int i = blockIdx.x * 256 + tid;
  int v = (i < Nn) ? rp[i] : 0;
  a[tid] = v;
  __syncthreads();
  int* s = a;
  int* d = b;
  for (int off = 1; off < 256; off <<= 1) {
    int t = s[tid] + ((tid >= off) ? s[tid - off] : 0);
    d[tid] = t;
    __syncthreads();
    int* tmp = s; s = d; d = tmp;
  }
  int incl = s[tid];
  if (i < Nn) rp[i] = incl - v;
  if (tid == 255) bsum[blockIdx.x] = incl;
}

// parallel single-block exclusive scan of block sums (nb <= 512)
__global__ __launch_bounds__(512) void k_scan2(int* __restrict__ bsum, int nb) {
  __shared__ int a[512], b[512];
  int tid = threadIdx.x;
  int v = (tid < nb) ? bsum[tid] : 0;
  a[tid] = v;
  __syncthreads();
  int* s = a;
  int* d = b;
  for (int off = 1; off < 512; off <<= 1) {
    int t = s[tid] + ((tid >= off) ? s[tid - off] : 0);
    d[tid] = t;
    __syncthreads();
    int* tmp = s; s = d; d = tmp;
  }
  if (tid < nb) bsum[tid] = s[tid] - v;
}

__global__ __launch_bounds__(256) void k_scan3(int* __restrict__ rp,
                                               int* __restrict__ cursor,
                                               const int* __restrict__ bsum,
                                               int Nn, int E) {
  int i = blockIdx.x * 256 + threadIdx.x;
  if (i < Nn) {
    int v = rp[i] + bsum[blockIdx.x];
    rp[i] = v;
    cursor[i] = v;
  }
  if (i == 0) rp[Nn] = E;
}

__global__ __launch_bounds__(256) void k_scatter(const int* __restrict__ ei,
                                                 int* __restrict__ cursor,
                                                 int* __restrict__ csr, int E) {
  int e = blockIdx.x * 256 + threadIdx.x;
  if (e >= E) return;
  int s = ei[e], d2 = ei[E + e];
  int idx = atomicAdd(&cursor[d2], 1);
  csr[idx] = s;
}

__device__ __forceinline__ float sigmoidf_(float v) {
  return 1.0f / (1.0f + __expf(-v));
}
__device__ __forceinline__ float bflo(unsigned w) {
  union { unsigned u; float f; } c; c.u = w << 16; return c.f;
}
__device__ __forceinline__ float bfhi(unsigned w) {
  union { unsigned u; float f; } c; c.u = w & 0xffff0000u; return c.f;
}
__device__ __forceinline__ unsigned short f2bf(float f) {
  union { float f; unsigned u; } c; c.f = f;
  unsigned r = c.u + 0x7fffu + ((c.u >> 16) & 1u);  // RNE
  return (unsigned short)(r >> 16);
}

// h1 = sigmoid(mean(x[nbrs]) @ W1l + b1l + x @ W1r) -> bf16. 1 node/wave.
__global__ __launch_bounds__(512, 8) void node1_fused(
    const float* __restrict__ x, const int* __restrict__ rp,
    const int* __restrict__ csr,
    const float* __restrict__ W1l, const float* __restrict__ b1l,
    const float* __restrict__ W1r,
    unsigned short* __restrict__ h1b, int n_nodes) {
  __shared__ float sWl[NF1 * HH];
  __shared__ float sWr[NF1 * HH];
  __shared__ float sb[HH];
  __shared__ float sm[8][NF1];
  __shared__ float sx[8][NF1];
  for (int i = threadIdx.x; i < NF1 * HH; i += 512) {
    sWl[i] = W1l[i];
    sWr[i] = W1r[i];
  }
  if (threadIdx.x < HH) sb[threadIdx.x] = b1l[threadIdx.x];
  __syncthreads();

  int wv = threadIdx.x >> 6, lane = threadIdx.x & 63;
  int g = lane >> 4, fl = lane & 15;

  for (int nbase = blockIdx.x * 8; nbase < n_nodes; nbase += gridDim.x * 8) {
    int node = nbase + wv;
    bool valid = node < n_nodes;
    int nn = valid ? node : (n_nodes - 1);
    int rs = rp[nn], re = rp[nn + 1];
    int deg = re - rs;

    float ax = 0.0f, ay = 0.0f, az = 0.0f, aw = 0.0f;
    for (int base = 0; base < deg; base += 64) {
      int c = min(deg - base, 64);
      int idxv = csr[rs + base + min(lane, c - 1)];
      int j = g;
      for (; j + 12 < c; j += 16) {
        int s0 = __shfl(idxv, j);
        int s1 = __shfl(idxv, j + 4);
        int s2 = __shfl(idxv, j + 8);
        int s3 = __shfl(idxv, j + 12);
        if (fl < 12) {
          float4 v0 = *((const float4*)(x + (size_t)s0 * NF1) + fl);
          float4 v1 = *((const float4*)(x + (size_t)s1 * NF1) + fl);
          float4 v2 = *((const float4*)(x + (size_t)s2 * NF1) + fl);
          float4 v3 = *((const float4*)(x + (size_t)s3 * NF1) + fl);
          ax += (v0.x + v1.x) + (v2.x + v3.x);
          ay += (v0.y + v1.y) + (v2.y + v3.y);
          az += (v0.z + v1.z) + (v2.z + v3.z);
          aw += (v0.w + v1.w) + (v2.w + v3.w);
        }
      }
      for (; j < c; j += 4) {
        int s0 = __shfl(idxv, j);
        if (fl < 12) {
          float4 v0 = *((const float4*)(x + (size_t)s0 * NF1) + fl);
          ax += v0.x; ay += v0.y; az += v0.z; aw += v0.w;
        }
      }
    }
    ax += __shfl_xor(ax, 16); ay += __shfl_xor(ay, 16);
    az += __shfl_xor(az, 16); aw += __shfl_xor(aw, 16);
    ax += __shfl_xor(ax, 32); ay += __shfl_xor(ay, 32);
    az += __shfl_xor(az, 32); aw += __shfl_xor(aw, 32);

    float inv = 1.0f / fmaxf((float)deg, 1.0f);
    if (lane < 12) {
      float4 m4 = {ax * inv, ay * inv, az * inv, aw * inv};
      ((float4*)sm[wv])[lane] = m4;
    }
    if (lane < NF1) sx[wv][lane] = x[(size_t)nn * NF1 + lane];
    __syncthreads();

    float acc = sb[lane];
#pragma unroll
    for (int k = 0; k < NF1; k++) {
      acc += sm[wv][k] * sWl[k * HH + lane] + sx[wv][k] * sWr[k * HH + lane];
    }
    if (valid) h1b[(size_t)node * HH + lane] = f2bf(sigmoidf_(acc));
    __syncthreads();
  }
}

// h2 = sigmoid(mean(h1[nbrs]) @ W2l + b2l + h1 @ W2r) -> f32
__global__ __launch_bounds__(512, 8) void node2_sage(
    const unsigned short* __restrict__ h1b, const int* __restrict__ rp,
    const int* __restrict__ csr,
    const float* __restrict__ W2l, const float* __restrict__ b2l,
    const float* __restrict__ W2r,
    float* __restrict__ h2, int n_nodes) {
  __shared__ float sW2l[HH * HH];
  __shared__ float sW2r[HH * HH];
  __shared__ float sb2[HH];
  __shared__ float sm[8][HH];
  __shared__ float sh[8][HH];
  for (int i = threadIdx.x; i < HH * HH; i += 512) {
    sW2l[i] = W2l[i];
    sW2r[i] = W2r[i];
  }
  if (threadIdx.x < HH) sb2[threadIdx.x] = b2l[threadIdx.x];
  __syncthreads();

  int wv = threadIdx.x >> 6, lane = threadIdx.x & 63;
  int g = lane >> 3, fl = lane & 7;

  for (int nbase = blockIdx.x * 8; nbase < n_nodes; nbase += gridDim.x * 8) {
    int node = nbase + wv;
    bool valid = node < n_nodes;
    int nn = valid ? node : (n_nodes - 1);
    int rs = rp[nn], re = rp[nn + 1];
    int deg = re - rs;

    float a0 = 0, a1 = 0, a2 = 0, a3 = 0, a4 = 0, a5 = 0, a6 = 0, a7 = 0;
    for (int base = 0; base < deg; base += 64) {
      int c = min(deg - base, 64);
      int idxv = csr[rs + base + min(lane, c - 1)];
      int j = g;
      for (; j + 8 < c; j += 16) {
        int s0 = __shfl(idxv, j);
        int s1 = __shfl(idxv, j + 8);
        uint4 r0 = *((const uint4*)(h1b + (size_t)s0 * HH) + fl);
        uint4 r1 = *((const uint4*)(h1b + (size_t)s1 * HH) + fl);
        a0 += bflo(r0.x) + bflo(r1.x); a1 += bfhi(r0.x) + bfhi(r1.x);
        a2 += bflo(r0.y) + bflo(r1.y); a3 += bfhi(r0.y) + bfhi(r1.y);
        a4 += bflo(r0.z) + bflo(r1.z); a5 += bfhi(r0.z) + bfhi(r1.z);
        a6 += bflo(r0.w) + bflo(r1.w); a7 += bfhi(r0.w) + bfhi(r1.w);
      }
      for (; j < c; j += 8) {
        int s0 = __shfl(idxv, j);
        uint4 r0 = *((const uint4*)(h1b + (size_t)s0 * HH) + fl);
        a0 += bflo(r0.x); a1 += bfhi(r0.x);
        a2 += bflo(r0.y); a3 += bfhi(r0.y);
        a4 += bflo(r0.z); a5 += bfhi(r0.z);
        a6 += bflo(r0.w); a7 += bfhi(r0.w);
      }
    }
    a0 += __shfl_xor(a0, 8); a1 += __shfl_xor(a1, 8);
    a2 += __shfl_xor(a2, 8); a3 += __shfl_xor(a3, 8);
    a4 += __shfl_xor(a4, 8); a5 += __shfl_xor(a5, 8);
    a6 += __shfl_xor(a6, 8); a7 += __shfl_xor(a7, 8);
    a0 += __shfl_xor(a0, 16); a1 += __shfl_xor(a1, 16);
    a2 += __shfl_xor(a2, 16); a3 += __shfl_xor(a3, 16);
    a4 += __shfl_xor(a4, 16); a5 += __shfl_xor(a5, 16);
    a6 += __shfl_xor(a6, 16); a7 += __shfl_xor(a7, 16);
    a0 += __shfl_xor(a0, 32); a1 += __shfl_xor(a1, 32);
    a2 += __shfl_xor(a2, 32); a3 += __shfl_xor(a3, 32);
    a4 += __shfl_xor(a4, 32); a5 += __shfl_xor(a5, 32);
    a6 += __shfl_xor(a6, 32); a7 += __shfl_xor(a7, 32);

    float inv = 1.0f / fmaxf((float)deg, 1.0f);
    if (lane < 8) {
      float4 m40 = {a0 * inv, a1 * inv, a2 * inv, a3 * inv};
      float4 m41 = {a4 * inv, a5 * inv, a6 * inv, a7 * inv};
      ((float4*)&sm[wv][lane * 8])[0] = m40;
      ((float4*)&sm[wv][lane * 8])[1] = m41;
    }
    sh[wv][lane] = bflo((unsigned)h1b[(size_t)nn * HH + lane] << 16 >> 16 << 16);
    // simpler: convert directly
    sh[wv][lane] = bflo(0) ;  // placeholder overwritten below
    {
      unsigned u = (unsigned)h1b[(size_t)nn * HH + lane];
      union { unsigned uu; float ff; } cc; cc.uu = u << 16;
      sh[wv][lane] = cc.ff;
    }
    __syncthreads();

    float acc = sb2[lane];
#pragma unroll
    for (int k = 0; k < HH; k++) {
      acc += sm[wv][k] * sW2l[k * HH + lane] + sh[wv][k] * sW2r[k * HH + lane];
    }
    if (valid) h2[(size_t)node * HH + lane] = sigmoidf_(acc);
    __syncthreads();
  }
}

// h3 = sigmoid(h2 @ Wlin1 + blin1); out = softmax(h3 @ Wlin2 + blin2)
__global__ __launch_bounds__(512, 8) void head_k(
    const float* __restrict__ h2,
    const float* __restrict__ Wlin1, const float* __restrict__ blin1,
    const float* __restrict__ Wlin2, const float* __restrict__ blin2,
    float* __restrict__ out, int n_nodes) {
  __shared__ float sWl1[HH * HH];
  __shared__ float sWl2[HH * 2];
  __shared__ float sbl1[HH], sbl2[2];
  __shared__ float sh2[8][HH];
  for (int i = threadIdx.x; i < HH * HH; i += 512) sWl1[i] = Wlin1[i];
  if (threadIdx.x < HH * 2) sWl2[threadIdx.x] = Wlin2[threadIdx.x];
  if (threadIdx.x < HH) sbl1[threadIdx.x] = blin1[threadIdx.x];
  if (threadIdx.x < 2) sbl2[threadIdx.x] = blin2[threadIdx.x];
  __syncthreads();

  int wv = threadIdx.x >> 6, lane = threadIdx.x & 63;
  for (int nbase = blockIdx.x * 8; nbase < n_nodes; nbase += gridDim.x * 8) {
    int node = nbase + wv;
    bool valid = node < n_nodes;
    int nn = valid ? node : (n_nodes - 1);
    sh2[wv][lane] = h2[(size_t)nn * HH + lane];
    __syncthreads();

    float acc3 = sbl1[lane];
#pragma unroll
    for (int k = 0; k < HH; k++) acc3 += sh2[wv][k] * sWl1[k * HH + lane];
    float h3 = sigmoidf_(acc3);

    float l0 = h3 * sWl2[lane * 2 + 0];
    float l1 = h3 * sWl2[lane * 2 + 1];
    for (int off = 32; off > 0; off >>= 1) {
      l0 += __shfl_xor(l0, off);
      l1 += __shfl_xor(l1, off);
    }
    if (valid && lane == 0) {
      l0 += sbl2[0];
      l1 += sbl2[1];
      float m = fmaxf(l0, l1);
      float p0 = __expf(l0 - m), p1 = __expf(l1 - m);
      float s = 1.0f / (p0 + p1);
      out[(size_t)node * 2 + 0] = p0 * s;
      out[(size_t)node * 2 + 1] = p1 * s;
    }
    __syncthreads();
  }
}

extern "C" void kernel_launch(void* const* d_in, const int* in_sizes, int n_in,
                              void* d_out, int out_size, void* d_ws, size_t ws_size,
                              hipStream_t stream) {
  const float* x     = (const float*)d_in[0];
  const int*   ei    = (const int*)d_in[1];
  const float* W1l   = (const float*)d_in[2];
  const float* b1l   = (const float*)d_in[3];
  const float* W1r   = (const float*)d_in[4];
  const float* W2l   = (const float*)d_in[5];
  const float* b2l   = (const float*)d_in[6];
  const float* W2r   = (const float*)d_in[7];
  const float* Wlin1 = (const float*)d_in[8];
  const float* blin1 = (const float*)d_in[9];
  const float* Wlin2 = (const float*)d_in[10];
  const float* blin2 = (const float*)d_in[11];
  float* out = (float*)d_out;

  int n = in_sizes[0] / NF1;
  int E = in_sizes[1] / 2;
  int nb = (n + 255) / 256;

  int* rp     = (int*)d_ws;                 // [n+1]
  int* cursor = rp + (n + 1);               // [n]
  int* bsum   = cursor + n;                 // [nb]
  int* csr    = bsum + nb;                  // [E]
  size_t off = (size_t)(n + 1 + n + nb + E) * sizeof(int);
  off = (off + 255) & ~(size_t)255;
  unsigned short* h1b = (unsigned short*)((char*)d_ws + off);  // [n,64] bf16
  off += (size_t)n * HH * sizeof(unsigned short);
  off = (off + 255) & ~(size_t)255;
  float* h2 = (float*)((char*)d_ws + off);  // [n,64] f32

  hipMemsetAsync(rp, 0, (size_t)(n + 1) * sizeof(int), stream);

  int eb = (E + 255) / 256;
  k_hist<<<eb, 256, 0, stream>>>(ei, rp, E);
  k_scan1<<<nb, 256, 0, stream>>>(rp, bsum, n);
  k_scan2<<<1, 512, 0, stream>>>(bsum, nb);
  k_scan3<<<nb, 256, 0, stream>>>(rp, cursor, bsum, n, E);
  k_scatter<<<eb, 256, 0, stream>>>(ei, cursor, csr, E);

  int nodeb = (n + 7) / 8;
  int grid = nodeb < 1024 ? nodeb : 1024;
  node1_fused<<<grid, 512, 0, stream>>>(x, rp, csr, W1l, b1l, W1r, h1b, n);
  node2_sage<<<grid, 512, 0, stream>>>(h1b, rp, csr, W2l, b2l, W2r, h2, n);
  head_k<<<grid, 512, 0, stream>>>(h2, Wlin1, blin1, Wlin2, blin2, out, n);
}